// Round 7
// baseline (381.502 us; speedup 1.0000x reference)
//
#include <hip/hip_runtime.h>
#include <hip/hip_fp16.h>

#define DDIM 64
#define EPS 0.1f
#define NORM_EPS 1e-12f

// ---------------- fallback init ----------------
__global__ void init_zero_kernel(const float* __restrict__ user, const float* __restrict__ item,
                                 float* __restrict__ egoA, float* __restrict__ egoB,
                                 int UD, int ND) {
    int i = blockIdx.x * blockDim.x + threadIdx.x;
    if (i < ND) {
        egoA[i] = (i < UD) ? user[i] : item[i - UD];
        egoB[i] = 0.0f;
    }
}

// ---------------- CSR build ----------------
__global__ void zero_int_kernel(int* __restrict__ p, int n) {
    int i = blockIdx.x * blockDim.x + threadIdx.x;
    if (i < n) p[i] = 0;
}

__global__ void hist_kernel(const int* __restrict__ row, int* __restrict__ cnt, int nnz) {
    int e = blockIdx.x * blockDim.x + threadIdx.x;
    if (e < nnz) atomicAdd(&cnt[row[e]], 1);
}

__global__ void scan1_kernel(const int* __restrict__ cnt, int* __restrict__ partial,
                             int* __restrict__ bsums, int n) {
    __shared__ int s[1024];
    int i = blockIdx.x * 1024 + threadIdx.x;
    int v = (i < n) ? cnt[i] : 0;
    s[threadIdx.x] = v;
    __syncthreads();
    for (int off = 1; off < 1024; off <<= 1) {
        int t = (threadIdx.x >= off) ? s[threadIdx.x - off] : 0;
        __syncthreads();
        s[threadIdx.x] += t;
        __syncthreads();
    }
    if (i < n) partial[i] = s[threadIdx.x];
    if (threadIdx.x == 1023) bsums[blockIdx.x] = s[1023];
}

__global__ void scan2_kernel(int* __restrict__ bsums, int nb) {
    if (blockIdx.x == 0 && threadIdx.x == 0) {
        int run = 0;
        for (int b = 0; b < nb; ++b) { int t = bsums[b]; bsums[b] = run; run += t; }
    }
}

__global__ void scan3_serialbs_kernel(const int* __restrict__ partial, const int* __restrict__ bsums,
                                      int* __restrict__ rowptr, int n) {
    int i = blockIdx.x * 1024 + threadIdx.x;
    if (i < n) rowptr[i + 1] = partial[i] + bsums[blockIdx.x];
    if (i == 0) rowptr[0] = 0;
}

__global__ void scan3_fused_kernel(const int* __restrict__ partial, const int* __restrict__ bsums,
                                   int* __restrict__ rowptr, int n, int nb) {
    __shared__ int s[1024];
    int t = threadIdx.x;
    s[t] = (t < nb && t < (int)blockIdx.x) ? bsums[t] : 0;
    __syncthreads();
    #pragma unroll
    for (int off = 512; off > 0; off >>= 1) {
        if (t < off) s[t] += s[t + off];
        __syncthreads();
    }
    int base = s[0];
    int i = blockIdx.x * 1024 + t;
    if (i < n) rowptr[i + 1] = partial[i] + base;
    if (i == 0) rowptr[0] = 0;
}

// reverse-fill scatter: cnt still holds per-row counts from hist
__global__ void scatter_kernel(const int* __restrict__ row, const int* __restrict__ col,
                               const float* __restrict__ val, const int* __restrict__ rowptr,
                               int* __restrict__ cnt, int2* __restrict__ edges, int nnz) {
    int e = blockIdx.x * blockDim.x + threadIdx.x;
    if (e < nnz) {
        int r = row[e];
        int old = atomicSub(&cnt[r], 1);
        edges[rowptr[r] + old - 1] = make_int2(col[e], __float_as_int(val[e]));
    }
}

// ---------------- fused layer ----------------
// fp32 acc += fp16x2-packed * fp32 scalar, one v_fma_mix_f32 per dim
__device__ __forceinline__ void fma_mix8(float& f0, float& f1, float& f2, float& f3,
                                         float& f4, float& f5, float& f6, float& f7,
                                         uint4 q, float v) {
    asm("v_fma_mix_f32 %0, %8, %12, %0 op_sel:[0,0,0] op_sel_hi:[1,0,0]\n\t"
        "v_fma_mix_f32 %1, %8, %12, %1 op_sel:[1,0,0] op_sel_hi:[1,0,0]\n\t"
        "v_fma_mix_f32 %2, %9, %12, %2 op_sel:[0,0,0] op_sel_hi:[1,0,0]\n\t"
        "v_fma_mix_f32 %3, %9, %12, %3 op_sel:[1,0,0] op_sel_hi:[1,0,0]\n\t"
        "v_fma_mix_f32 %4, %10, %12, %4 op_sel:[0,0,0] op_sel_hi:[1,0,0]\n\t"
        "v_fma_mix_f32 %5, %10, %12, %5 op_sel:[1,0,0] op_sel_hi:[1,0,0]\n\t"
        "v_fma_mix_f32 %6, %11, %12, %6 op_sel:[0,0,0] op_sel_hi:[1,0,0]\n\t"
        "v_fma_mix_f32 %7, %11, %12, %7 op_sel:[1,0,0] op_sel_hi:[1,0,0]"
        : "+v"(f0), "+v"(f1), "+v"(f2), "+v"(f3),
          "+v"(f4), "+v"(f5), "+v"(f6), "+v"(f7)
        : "v"(q.x), "v"(q.y), "v"(q.z), "v"(q.w), "v"(v));
}

__device__ __forceinline__ void h2f8(uint4 q, float o[8]) {
    float2 t;
    t = __half22float2(*reinterpret_cast<const __half2*>(&q.x)); o[0] = t.x; o[1] = t.y;
    t = __half22float2(*reinterpret_cast<const __half2*>(&q.y)); o[2] = t.x; o[3] = t.y;
    t = __half22float2(*reinterpret_cast<const __half2*>(&q.z)); o[4] = t.x; o[5] = t.y;
    t = __half22float2(*reinterpret_cast<const __half2*>(&q.w)); o[6] = t.x; o[7] = t.y;
}

// one row per 8-lane group (8 rows/wave); lane sub owns dims [sub*8, sub*8+8).
// XHALF=0: gather fp32 user/item (layer 0). XHALF=1: gather fp16 ego.
// FINAL=0: write perturbed ego to y16.  FINAL=1: fold mean over (yprev0,yprev1,ep) into out4.
template <int XHALF, int FINAL>
__global__ void fused_layer_kernel(const int* __restrict__ rowptr, const int2* __restrict__ edges,
                                   const float4* __restrict__ xu4, const float4* __restrict__ xi4,
                                   int splitRow,
                                   const uint4* __restrict__ x16,
                                   const float4* __restrict__ noise4,
                                   uint4* __restrict__ y16,
                                   const uint4* __restrict__ yprev0, const uint4* __restrict__ yprev1,
                                   float4* __restrict__ out4,
                                   int N, float invL) {
    int lane = threadIdx.x & 63;
    int wid = (blockIdx.x * blockDim.x + threadIdx.x) >> 6;
    int g   = lane >> 3;   // group = row slot 0..7
    int sub = lane & 7;    // 8-dim chunk within row
    int r = wid * 8 + g;
    bool active = r < N;

    size_t f4idx = (size_t)r * 16 + sub * 2;
    size_t hidx  = (size_t)r * 8 + sub;

    // prologue loads (issued early, overlap with gather)
    float4 nva = make_float4(0.f,0.f,0.f,0.f), nvb = make_float4(0.f,0.f,0.f,0.f);
    uint4 qp0 = make_uint4(0,0,0,0), qp1 = make_uint4(0,0,0,0);
    int beg = 0, end = 0;
    if (active) {
        beg = rowptr[r];
        end = rowptr[r + 1];
        nva = noise4[f4idx]; nvb = noise4[f4idx + 1];
        if (FINAL) { qp0 = yprev0[hidx]; qp1 = yprev1[hidx]; }
    }

    float f0=0.f,f1=0.f,f2=0.f,f3=0.f,f4=0.f,f5=0.f,f6=0.f,f7=0.f;

    int e = beg;
    if (XHALF) {
        while (e + 2 <= end) {
            int2 ed0 = edges[e];
            int2 ed1 = edges[e + 1];
            uint4 q0 = x16[(size_t)ed0.x * 8 + sub];
            uint4 q1 = x16[(size_t)ed1.x * 8 + sub];
            fma_mix8(f0,f1,f2,f3,f4,f5,f6,f7, q0, __int_as_float(ed0.y));
            fma_mix8(f0,f1,f2,f3,f4,f5,f6,f7, q1, __int_as_float(ed1.y));
            e += 2;
        }
        if (e < end) {
            int2 ed = edges[e];
            uint4 q = x16[(size_t)ed.x * 8 + sub];
            fma_mix8(f0,f1,f2,f3,f4,f5,f6,f7, q, __int_as_float(ed.y));
        }
    } else {
        while (e < end) {
            int2 ed = edges[e];
            float v = __int_as_float(ed.y);
            const float4* s = (ed.x < splitRow) ? (xu4 + (size_t)ed.x * 16)
                                                : (xi4 + (size_t)(ed.x - splitRow) * 16);
            float4 a = s[sub * 2], b = s[sub * 2 + 1];
            f0 = fmaf(v, a.x, f0); f1 = fmaf(v, a.y, f1);
            f2 = fmaf(v, a.z, f2); f3 = fmaf(v, a.w, f3);
            f4 = fmaf(v, b.x, f4); f5 = fmaf(v, b.y, f5);
            f6 = fmaf(v, b.z, f6); f7 = fmaf(v, b.w, f7);
            ++e;
        }
    }

    // noise L2 norm over the row: local 8 dims + 3-step intra-group reduce
    float sq = nva.x*nva.x + nva.y*nva.y + nva.z*nva.z + nva.w*nva.w
             + nvb.x*nvb.x + nvb.y*nvb.y + nvb.z*nvb.z + nvb.w*nvb.w;
    #pragma unroll
    for (int off = 1; off <= 4; off <<= 1) sq += __shfl_xor(sq, off, 64);
    float scale = EPS / fmaxf(sqrtf(sq), NORM_EPS);

    float acc[8] = {f0,f1,f2,f3,f4,f5,f6,f7};
    float nse[8] = {nva.x,nva.y,nva.z,nva.w,nvb.x,nvb.y,nvb.z,nvb.w};
    float ep[8];
    #pragma unroll
    for (int i = 0; i < 8; ++i) {
        float s = (acc[i] > 0.f) ? 1.f : ((acc[i] < 0.f) ? -1.f : 0.f);
        ep[i] = acc[i] + s * nse[i] * scale;
    }

    if (active) {
        if (FINAL) {
            float p0[8], p1[8];
            h2f8(qp0, p0);
            h2f8(qp1, p1);
            float4 oa, ob;
            oa.x = (p0[0] + p1[0] + ep[0]) * invL;
            oa.y = (p0[1] + p1[1] + ep[1]) * invL;
            oa.z = (p0[2] + p1[2] + ep[2]) * invL;
            oa.w = (p0[3] + p1[3] + ep[3]) * invL;
            ob.x = (p0[4] + p1[4] + ep[4]) * invL;
            ob.y = (p0[5] + p1[5] + ep[5]) * invL;
            ob.z = (p0[6] + p1[6] + ep[6]) * invL;
            ob.w = (p0[7] + p1[7] + ep[7]) * invL;
            out4[f4idx] = oa;
            out4[f4idx + 1] = ob;
        } else {
            __half2 h0 = __floats2half2_rn(ep[0], ep[1]);
            __half2 h1 = __floats2half2_rn(ep[2], ep[3]);
            __half2 h2 = __floats2half2_rn(ep[4], ep[5]);
            __half2 h3 = __floats2half2_rn(ep[6], ep[7]);
            uint4 st;
            st.x = *reinterpret_cast<unsigned*>(&h0);
            st.y = *reinterpret_cast<unsigned*>(&h1);
            st.z = *reinterpret_cast<unsigned*>(&h2);
            st.w = *reinterpret_cast<unsigned*>(&h3);
            y16[hidx] = st;
        }
    }
}

// ---------------- fallback path (round-1 kernels) ----------------
__global__ void spmm_kernel(const int* __restrict__ row, const int* __restrict__ col,
                            const float* __restrict__ val, const float* __restrict__ x,
                            float* __restrict__ y, int nnz) {
    int gtid = blockIdx.x * blockDim.x + threadIdx.x;
    int wid = gtid >> 6;
    int lane = threadIdx.x & 63;
    int nwaves = (gridDim.x * blockDim.x) >> 6;
    for (int e = wid; e < nnz; e += nwaves) {
        int r = row[e];
        int c = col[e];
        float v = val[e];
        unsafeAtomicAdd(&y[(size_t)r * DDIM + lane], v * x[(size_t)c * DDIM + lane]);
    }
}

__global__ void perturb_kernel(float* __restrict__ ego, const float* __restrict__ noise,
                               float* __restrict__ zero_buf, float* __restrict__ out,
                               int N, int first, float invL) {
    int gtid = blockIdx.x * blockDim.x + threadIdx.x;
    int wid = gtid >> 6;
    int lane = threadIdx.x & 63;
    int nwaves = (gridDim.x * blockDim.x) >> 6;
    for (int n = wid; n < N; n += nwaves) {
        size_t idx = (size_t)n * DDIM + lane;
        float nv = noise[idx];
        float sq = nv * nv;
        #pragma unroll
        for (int off = 32; off > 0; off >>= 1) sq += __shfl_xor(sq, off, 64);
        float rn = nv / fmaxf(sqrtf(sq), NORM_EPS);
        float e = ego[idx];
        float s = (e > 0.0f) ? 1.0f : ((e < 0.0f) ? -1.0f : 0.0f);
        float ep = e + s * rn * EPS;
        ego[idx] = ep;
        if (zero_buf) zero_buf[idx] = 0.0f;
        float o = ep * invL;
        out[idx] = first ? o : (out[idx] + o);
    }
}

extern "C" void kernel_launch(void* const* d_in, const int* in_sizes, int n_in,
                              void* d_out, int out_size, void* d_ws, size_t ws_size,
                              hipStream_t stream) {
    const float* user  = (const float*)d_in[0];
    const float* item  = (const float*)d_in[1];
    const int*   row   = (const int*)d_in[2];
    const int*   col   = (const int*)d_in[3];
    const float* val   = (const float*)d_in[4];
    const float* noise = (const float*)d_in[5];
    float* out = (float*)d_out;

    int UD = in_sizes[0];
    int ID = in_sizes[1];
    int ND = UD + ID;
    int N  = ND / DDIM;
    int nnz = in_sizes[2];
    int L  = in_sizes[5] / ND;
    float invL = 1.0f / (float)L;

    // ws layout (4B units):
    // y16[0..2] (3 * ND/2) | rowptr(N+2) | cnt(N) | partial(N) | bsums(1024) | edges(2*nnz)
    size_t ND_ = (size_t)ND;
    size_t ofs_rowptr  = (3 * ND_) / 2;
    size_t ofs_cnt     = ofs_rowptr + (size_t)(N + 2);
    size_t ofs_partial = ofs_cnt + (size_t)N;
    size_t ofs_bsums   = ofs_partial + (size_t)N;
    size_t ofs_edges   = ofs_bsums + 1024;
    size_t needed = (ofs_edges + 2ull * (size_t)nnz) * 4ull;

    if (ws_size >= needed && (N % 2) == 0 && (UD % DDIM) == 0 && L == 3) {
        uint4* ybase = (uint4*)d_ws;                 // each buffer: N*8 uint4 = ND/2 floats
        size_t ystride = (size_t)N * 8;
        uint4* y0 = ybase;
        uint4* y1 = ybase + ystride;
        uint4* y2 = ybase + 2 * ystride;  // unused (final folds), kept for layout clarity
        (void)y2;
        int* rowptr  = (int*)d_ws + ofs_rowptr;
        int* cnt     = (int*)d_ws + ofs_cnt;
        int* partial = (int*)d_ws + ofs_partial;
        int* bsums   = (int*)d_ws + ofs_bsums;
        int2* edges  = (int2*)((int*)d_ws + ofs_edges);

        int nb = (N + 1023) / 1024;

        zero_int_kernel<<<(N + 255) / 256, 256, 0, stream>>>(cnt, N);
        hist_kernel<<<(nnz + 255) / 256, 256, 0, stream>>>(row, cnt, nnz);
        scan1_kernel<<<nb, 1024, 0, stream>>>(cnt, partial, bsums, N);
        if (nb <= 1024) {
            scan3_fused_kernel<<<nb, 1024, 0, stream>>>(partial, bsums, rowptr, N, nb);
        } else {
            scan2_kernel<<<1, 64, 0, stream>>>(bsums, nb);
            scan3_serialbs_kernel<<<nb, 1024, 0, stream>>>(partial, bsums, rowptr, N);
        }
        // cnt still holds counts -> reverse-fill cursor
        scatter_kernel<<<(nnz + 255) / 256, 256, 0, stream>>>(row, col, val, rowptr, cnt, edges, nnz);

        const float4* user4 = (const float4*)user;
        const float4* item4 = (const float4*)item;
        const float4* noise4 = (const float4*)noise;
        float4* out4 = (float4*)out;
        int Urows = UD / DDIM;
        size_t nzstride = ND_ / 4;

        int blocks = ((N * 8) + 255) / 256;   // 8 rows per wave

        // layer 0: gather fp32 user/item -> y0
        fused_layer_kernel<0, 0><<<blocks, 256, 0, stream>>>(
            rowptr, edges, user4, item4, Urows, nullptr,
            noise4, y0, nullptr, nullptr, nullptr, N, invL);
        // layer 1: gather fp16 y0 -> y1
        fused_layer_kernel<1, 0><<<blocks, 256, 0, stream>>>(
            rowptr, edges, nullptr, nullptr, 0, y0,
            noise4 + nzstride, y1, nullptr, nullptr, nullptr, N, invL);
        // layer 2: gather fp16 y1; fold mean(y0, y1, ep) -> out
        fused_layer_kernel<1, 1><<<blocks, 256, 0, stream>>>(
            rowptr, edges, nullptr, nullptr, 0, y1,
            noise4 + 2 * nzstride, nullptr, y0, y1, out4, N, invL);
    } else {
        // fallback: round-1 atomic path (fp32 throughout)
        float* egoA = (float*)d_ws;
        float* egoB = egoA + ND_;
        init_zero_kernel<<<(ND + 255) / 256, 256, 0, stream>>>(user, item, egoA, egoB, UD, ND);
        float* cur = egoA;
        float* nxt = egoB;
        for (int k = 0; k < L; ++k) {
            spmm_kernel<<<2048, 256, 0, stream>>>(row, col, val, cur, nxt, nnz);
            perturb_kernel<<<1024, 256, 0, stream>>>(
                nxt, noise + (size_t)k * ND_,
                (k + 1 < L) ? cur : nullptr, out, N, (k == 0) ? 1 : 0, invL);
            float* t = cur; cur = nxt; nxt = t;
        }
    }
}

// Round 8
// 325.473 us; speedup vs baseline: 1.1721x; 1.1721x over previous
//
#include <hip/hip_runtime.h>
#include <hip/hip_fp16.h>

#define DDIM 64
#define EPS 0.1f
#define NORM_EPS 1e-12f

// ---------------- fallback init ----------------
__global__ void init_zero_kernel(const float* __restrict__ user, const float* __restrict__ item,
                                 float* __restrict__ egoA, float* __restrict__ egoB,
                                 int UD, int ND) {
    int i = blockIdx.x * blockDim.x + threadIdx.x;
    if (i < ND) {
        egoA[i] = (i < UD) ? user[i] : item[i - UD];
        egoB[i] = 0.0f;
    }
}

// ---------------- CSR build ----------------
__global__ void zero_int_kernel(int* __restrict__ p, int n) {
    int i = blockIdx.x * blockDim.x + threadIdx.x;
    if (i < n) p[i] = 0;
}

// histogram + per-edge position within its row
__global__ void hist_kernel(const int* __restrict__ row, int* __restrict__ cnt,
                            int* __restrict__ pos, int nnz) {
    int e = blockIdx.x * blockDim.x + threadIdx.x;
    if (e < nnz) pos[e] = atomicAdd(&cnt[row[e]], 1);
}

__global__ void scan1_kernel(const int* __restrict__ cnt, int* __restrict__ partial,
                             int* __restrict__ bsums, int n) {
    __shared__ int s[1024];
    int i = blockIdx.x * 1024 + threadIdx.x;
    int v = (i < n) ? cnt[i] : 0;
    s[threadIdx.x] = v;
    __syncthreads();
    for (int off = 1; off < 1024; off <<= 1) {
        int t = (threadIdx.x >= off) ? s[threadIdx.x - off] : 0;
        __syncthreads();
        s[threadIdx.x] += t;
        __syncthreads();
    }
    if (i < n) partial[i] = s[threadIdx.x];
    if (threadIdx.x == 1023) bsums[blockIdx.x] = s[1023];
}

__global__ void scan2_kernel(int* __restrict__ bsums, int nb) {
    if (blockIdx.x == 0 && threadIdx.x == 0) {
        int run = 0;
        for (int b = 0; b < nb; ++b) { int t = bsums[b]; bsums[b] = run; run += t; }
    }
}

__global__ void scan3_serialbs_kernel(const int* __restrict__ partial, const int* __restrict__ bsums,
                                      int* __restrict__ rowptr, int n) {
    int i = blockIdx.x * 1024 + threadIdx.x;
    if (i < n) rowptr[i + 1] = partial[i] + bsums[blockIdx.x];
    if (i == 0) rowptr[0] = 0;
}

__global__ void scan3_fused_kernel(const int* __restrict__ partial, const int* __restrict__ bsums,
                                   int* __restrict__ rowptr, int n, int nb) {
    __shared__ int s[1024];
    int t = threadIdx.x;
    s[t] = (t < nb && t < (int)blockIdx.x) ? bsums[t] : 0;
    __syncthreads();
    #pragma unroll
    for (int off = 512; off > 0; off >>= 1) {
        if (t < off) s[t] += s[t + off];
        __syncthreads();
    }
    int base = s[0];
    int i = blockIdx.x * 1024 + t;
    if (i < n) rowptr[i + 1] = partial[i] + base;
    if (i == 0) rowptr[0] = 0;
}

// atomic-free scatter using precomputed per-row positions
__global__ void scatter_kernel(const int* __restrict__ row, const int* __restrict__ col,
                               const float* __restrict__ val, const int* __restrict__ rowptr,
                               const int* __restrict__ pos, int2* __restrict__ edges, int nnz) {
    int e = blockIdx.x * blockDim.x + threadIdx.x;
    if (e < nnz) {
        int r = row[e];
        edges[rowptr[r] + pos[e]] = make_int2(col[e], __float_as_int(val[e]));
    }
}

// ---------------- fused layer ----------------
// fp32 acc += fp16x2-packed * fp32 scalar, one v_fma_mix_f32 per dim
__device__ __forceinline__ void fma_mix8(float& f0, float& f1, float& f2, float& f3,
                                         float& f4, float& f5, float& f6, float& f7,
                                         uint4 q, float v) {
    asm("v_fma_mix_f32 %0, %8, %12, %0 op_sel:[0,0,0] op_sel_hi:[1,0,0]\n\t"
        "v_fma_mix_f32 %1, %8, %12, %1 op_sel:[1,0,0] op_sel_hi:[1,0,0]\n\t"
        "v_fma_mix_f32 %2, %9, %12, %2 op_sel:[0,0,0] op_sel_hi:[1,0,0]\n\t"
        "v_fma_mix_f32 %3, %9, %12, %3 op_sel:[1,0,0] op_sel_hi:[1,0,0]\n\t"
        "v_fma_mix_f32 %4, %10, %12, %4 op_sel:[0,0,0] op_sel_hi:[1,0,0]\n\t"
        "v_fma_mix_f32 %5, %10, %12, %5 op_sel:[1,0,0] op_sel_hi:[1,0,0]\n\t"
        "v_fma_mix_f32 %6, %11, %12, %6 op_sel:[0,0,0] op_sel_hi:[1,0,0]\n\t"
        "v_fma_mix_f32 %7, %11, %12, %7 op_sel:[1,0,0] op_sel_hi:[1,0,0]"
        : "+v"(f0), "+v"(f1), "+v"(f2), "+v"(f3),
          "+v"(f4), "+v"(f5), "+v"(f6), "+v"(f7)
        : "v"(q.x), "v"(q.y), "v"(q.z), "v"(q.w), "v"(v));
}

__device__ __forceinline__ void h2f8(uint4 q, float o[8]) {
    float2 t;
    t = __half22float2(*reinterpret_cast<const __half2*>(&q.x)); o[0] = t.x; o[1] = t.y;
    t = __half22float2(*reinterpret_cast<const __half2*>(&q.y)); o[2] = t.x; o[3] = t.y;
    t = __half22float2(*reinterpret_cast<const __half2*>(&q.z)); o[4] = t.x; o[5] = t.y;
    t = __half22float2(*reinterpret_cast<const __half2*>(&q.w)); o[6] = t.x; o[7] = t.y;
}

// one row per 8-lane group (8 rows/wave); lane sub owns dims [sub*8, sub*8+8).
// XHALF=0: gather fp32 user/item (layer 0). XHALF=1: gather fp16 ego.
// FINAL=0: write perturbed ego to y16.  FINAL=1: fold mean over (yprev0,yprev1,ep) into out4.
template <int XHALF, int FINAL>
__global__ void fused_layer_kernel(const int* __restrict__ rowptr, const int2* __restrict__ edges,
                                   const float4* __restrict__ xu4, const float4* __restrict__ xi4,
                                   int splitRow,
                                   const uint4* __restrict__ x16,
                                   const float4* __restrict__ noise4,
                                   uint4* __restrict__ y16,
                                   const uint4* __restrict__ yprev0, const uint4* __restrict__ yprev1,
                                   float4* __restrict__ out4,
                                   int N, float invL) {
    int lane = threadIdx.x & 63;
    int wid = (blockIdx.x * blockDim.x + threadIdx.x) >> 6;
    int g   = lane >> 3;   // group = row slot 0..7
    int sub = lane & 7;    // 8-dim chunk within row
    int r = wid * 8 + g;
    bool active = r < N;

    size_t f4idx = (size_t)r * 16 + sub * 2;
    size_t hidx  = (size_t)r * 8 + sub;

    // prologue loads (issued early, overlap with gather)
    float4 nva = make_float4(0.f,0.f,0.f,0.f), nvb = make_float4(0.f,0.f,0.f,0.f);
    uint4 qp0 = make_uint4(0,0,0,0), qp1 = make_uint4(0,0,0,0);
    int beg = 0, end = 0;
    if (active) {
        beg = rowptr[r];
        end = rowptr[r + 1];
        nva = noise4[f4idx]; nvb = noise4[f4idx + 1];
        if (FINAL) { qp0 = yprev0[hidx]; qp1 = yprev1[hidx]; }
    }

    float f0=0.f,f1=0.f,f2=0.f,f3=0.f,f4=0.f,f5=0.f,f6=0.f,f7=0.f;

    int e = beg;
    if (XHALF) {
        while (e + 2 <= end) {
            int2 ed0 = edges[e];
            int2 ed1 = edges[e + 1];
            uint4 q0 = x16[(size_t)ed0.x * 8 + sub];
            uint4 q1 = x16[(size_t)ed1.x * 8 + sub];
            fma_mix8(f0,f1,f2,f3,f4,f5,f6,f7, q0, __int_as_float(ed0.y));
            fma_mix8(f0,f1,f2,f3,f4,f5,f6,f7, q1, __int_as_float(ed1.y));
            e += 2;
        }
        if (e < end) {
            int2 ed = edges[e];
            uint4 q = x16[(size_t)ed.x * 8 + sub];
            fma_mix8(f0,f1,f2,f3,f4,f5,f6,f7, q, __int_as_float(ed.y));
        }
    } else {
        while (e < end) {
            int2 ed = edges[e];
            float v = __int_as_float(ed.y);
            const float4* s = (ed.x < splitRow) ? (xu4 + (size_t)ed.x * 16)
                                                : (xi4 + (size_t)(ed.x - splitRow) * 16);
            float4 a = s[sub * 2], b = s[sub * 2 + 1];
            f0 = fmaf(v, a.x, f0); f1 = fmaf(v, a.y, f1);
            f2 = fmaf(v, a.z, f2); f3 = fmaf(v, a.w, f3);
            f4 = fmaf(v, b.x, f4); f5 = fmaf(v, b.y, f5);
            f6 = fmaf(v, b.z, f6); f7 = fmaf(v, b.w, f7);
            ++e;
        }
    }

    // noise L2 norm over the row: local 8 dims + 3-step intra-group reduce
    float sq = nva.x*nva.x + nva.y*nva.y + nva.z*nva.z + nva.w*nva.w
             + nvb.x*nvb.x + nvb.y*nvb.y + nvb.z*nvb.z + nvb.w*nvb.w;
    #pragma unroll
    for (int off = 1; off <= 4; off <<= 1) sq += __shfl_xor(sq, off, 64);
    float scale = EPS / fmaxf(sqrtf(sq), NORM_EPS);

    float acc[8] = {f0,f1,f2,f3,f4,f5,f6,f7};
    float nse[8] = {nva.x,nva.y,nva.z,nva.w,nvb.x,nvb.y,nvb.z,nvb.w};
    float ep[8];
    #pragma unroll
    for (int i = 0; i < 8; ++i) {
        float s = (acc[i] > 0.f) ? 1.f : ((acc[i] < 0.f) ? -1.f : 0.f);
        ep[i] = acc[i] + s * nse[i] * scale;
    }

    if (active) {
        if (FINAL) {
            float p0[8], p1[8];
            h2f8(qp0, p0);
            h2f8(qp1, p1);
            float4 oa, ob;
            oa.x = (p0[0] + p1[0] + ep[0]) * invL;
            oa.y = (p0[1] + p1[1] + ep[1]) * invL;
            oa.z = (p0[2] + p1[2] + ep[2]) * invL;
            oa.w = (p0[3] + p1[3] + ep[3]) * invL;
            ob.x = (p0[4] + p1[4] + ep[4]) * invL;
            ob.y = (p0[5] + p1[5] + ep[5]) * invL;
            ob.z = (p0[6] + p1[6] + ep[6]) * invL;
            ob.w = (p0[7] + p1[7] + ep[7]) * invL;
            out4[f4idx] = oa;
            out4[f4idx + 1] = ob;
        } else {
            __half2 h0 = __floats2half2_rn(ep[0], ep[1]);
            __half2 h1 = __floats2half2_rn(ep[2], ep[3]);
            __half2 h2 = __floats2half2_rn(ep[4], ep[5]);
            __half2 h3 = __floats2half2_rn(ep[6], ep[7]);
            uint4 st;
            st.x = *reinterpret_cast<unsigned*>(&h0);
            st.y = *reinterpret_cast<unsigned*>(&h1);
            st.z = *reinterpret_cast<unsigned*>(&h2);
            st.w = *reinterpret_cast<unsigned*>(&h3);
            y16[hidx] = st;
        }
    }
}

// ---------------- fallback path (round-1 kernels) ----------------
__global__ void spmm_kernel(const int* __restrict__ row, const int* __restrict__ col,
                            const float* __restrict__ val, const float* __restrict__ x,
                            float* __restrict__ y, int nnz) {
    int gtid = blockIdx.x * blockDim.x + threadIdx.x;
    int wid = gtid >> 6;
    int lane = threadIdx.x & 63;
    int nwaves = (gridDim.x * blockDim.x) >> 6;
    for (int e = wid; e < nnz; e += nwaves) {
        int r = row[e];
        int c = col[e];
        float v = val[e];
        unsafeAtomicAdd(&y[(size_t)r * DDIM + lane], v * x[(size_t)c * DDIM + lane]);
    }
}

__global__ void perturb_kernel(float* __restrict__ ego, const float* __restrict__ noise,
                               float* __restrict__ zero_buf, float* __restrict__ out,
                               int N, int first, float invL) {
    int gtid = blockIdx.x * blockDim.x + threadIdx.x;
    int wid = gtid >> 6;
    int lane = threadIdx.x & 63;
    int nwaves = (gridDim.x * blockDim.x) >> 6;
    for (int n = wid; n < N; n += nwaves) {
        size_t idx = (size_t)n * DDIM + lane;
        float nv = noise[idx];
        float sq = nv * nv;
        #pragma unroll
        for (int off = 32; off > 0; off >>= 1) sq += __shfl_xor(sq, off, 64);
        float rn = nv / fmaxf(sqrtf(sq), NORM_EPS);
        float e = ego[idx];
        float s = (e > 0.0f) ? 1.0f : ((e < 0.0f) ? -1.0f : 0.0f);
        float ep = e + s * rn * EPS;
        ego[idx] = ep;
        if (zero_buf) zero_buf[idx] = 0.0f;
        float o = ep * invL;
        out[idx] = first ? o : (out[idx] + o);
    }
}

extern "C" void kernel_launch(void* const* d_in, const int* in_sizes, int n_in,
                              void* d_out, int out_size, void* d_ws, size_t ws_size,
                              hipStream_t stream) {
    const float* user  = (const float*)d_in[0];
    const float* item  = (const float*)d_in[1];
    const int*   row   = (const int*)d_in[2];
    const int*   col   = (const int*)d_in[3];
    const float* val   = (const float*)d_in[4];
    const float* noise = (const float*)d_in[5];
    float* out = (float*)d_out;

    int UD = in_sizes[0];
    int ID = in_sizes[1];
    int ND = UD + ID;
    int N  = ND / DDIM;
    int nnz = in_sizes[2];
    int L  = in_sizes[5] / ND;
    float invL = 1.0f / (float)L;

    // ws layout (4B units):
    // y16[0..1] (2 * ND/2 = ND) | rowptr(N+2) | cnt(N) | partial(N) | bsums(1024) | pos(nnz) | edges(2*nnz)
    size_t ND_ = (size_t)ND;
    size_t ofs_rowptr  = ND_;
    size_t ofs_cnt     = ofs_rowptr + (size_t)(N + 2);
    size_t ofs_partial = ofs_cnt + (size_t)N;
    size_t ofs_bsums   = ofs_partial + (size_t)N;
    size_t ofs_pos     = ofs_bsums + 1024;
    size_t ofs_edges   = ofs_pos + (size_t)nnz;
    size_t needed = (ofs_edges + 2ull * (size_t)nnz) * 4ull;

    if (ws_size >= needed && (N % 2) == 0 && (UD % DDIM) == 0 && L == 3) {
        uint4* ybase = (uint4*)d_ws;                 // each buffer: N*8 uint4 = ND/2 floats
        size_t ystride = (size_t)N * 8;
        uint4* y0 = ybase;
        uint4* y1 = ybase + ystride;
        int* rowptr  = (int*)d_ws + ofs_rowptr;
        int* cnt     = (int*)d_ws + ofs_cnt;
        int* partial = (int*)d_ws + ofs_partial;
        int* bsums   = (int*)d_ws + ofs_bsums;
        int* pos     = (int*)d_ws + ofs_pos;
        int2* edges  = (int2*)((int*)d_ws + ofs_edges);

        int nb = (N + 1023) / 1024;

        zero_int_kernel<<<(N + 255) / 256, 256, 0, stream>>>(cnt, N);
        hist_kernel<<<(nnz + 255) / 256, 256, 0, stream>>>(row, cnt, pos, nnz);
        scan1_kernel<<<nb, 1024, 0, stream>>>(cnt, partial, bsums, N);
        if (nb <= 1024) {
            scan3_fused_kernel<<<nb, 1024, 0, stream>>>(partial, bsums, rowptr, N, nb);
        } else {
            scan2_kernel<<<1, 64, 0, stream>>>(bsums, nb);
            scan3_serialbs_kernel<<<nb, 1024, 0, stream>>>(partial, bsums, rowptr, N);
        }
        scatter_kernel<<<(nnz + 255) / 256, 256, 0, stream>>>(row, col, val, rowptr, pos, edges, nnz);

        const float4* user4 = (const float4*)user;
        const float4* item4 = (const float4*)item;
        const float4* noise4 = (const float4*)noise;
        float4* out4 = (float4*)out;
        int Urows = UD / DDIM;
        size_t nzstride = ND_ / 4;

        int blocks = ((N * 8) + 255) / 256;   // 8 rows per wave

        // layer 0: gather fp32 user/item -> y0
        fused_layer_kernel<0, 0><<<blocks, 256, 0, stream>>>(
            rowptr, edges, user4, item4, Urows, nullptr,
            noise4, y0, nullptr, nullptr, nullptr, N, invL);
        // layer 1: gather fp16 y0 -> y1
        fused_layer_kernel<1, 0><<<blocks, 256, 0, stream>>>(
            rowptr, edges, nullptr, nullptr, 0, y0,
            noise4 + nzstride, y1, nullptr, nullptr, nullptr, N, invL);
        // layer 2: gather fp16 y1; fold mean(y0, y1, ep) -> out
        fused_layer_kernel<1, 1><<<blocks, 256, 0, stream>>>(
            rowptr, edges, nullptr, nullptr, 0, y1,
            noise4 + 2 * nzstride, nullptr, y0, y1, out4, N, invL);
    } else {
        // fallback: round-1 atomic path (fp32 throughout)
        float* egoA = (float*)d_ws;
        float* egoB = egoA + ND_;
        init_zero_kernel<<<(ND + 255) / 256, 256, 0, stream>>>(user, item, egoA, egoB, UD, ND);
        float* cur = egoA;
        float* nxt = egoB;
        for (int k = 0; k < L; ++k) {
            spmm_kernel<<<2048, 256, 0, stream>>>(row, col, val, cur, nxt, nnz);
            perturb_kernel<<<1024, 256, 0, stream>>>(
                nxt, noise + (size_t)k * ND_,
                (k + 1 < L) ? cur : nullptr, out, N, (k == 0) ? 1 : 0, invL);
            float* t = cur; cur = nxt; nxt = t;
        }
    }
}